// Round 12
// baseline (190.859 us; speedup 1.0000x reference)
//
#include <hip/hip_runtime.h>
#include <math.h>

#define NR 5
#define NB 7
#define NS 119
#define NA 25000
#define NE 1000000
#define OC 360           // output columns per atom
#define MUS 100          // unique moment floats per atom
#define CAPR 96          // record bin capacity (lambda=40, max ~68, overflow ~1e-15)
#define CAPI 112         // id bin capacity (fallback path)
#define CHUNK 64         // atoms per accum/contract block
#define MPAD 101         // LDS stride: gcd(101,32)=1 -> conflict-free

// tril index tables (wave-uniform index -> scalar loads)
static constexpr int T2I[15] = {0,1,1,2,2,2,3,3,3,3,4,4,4,4,4};
static constexpr int T2J[15] = {0,0,1,0,1,2,0,1,2,3,0,1,2,3,4};
static constexpr int T3I[35] = {0,1,1,1,2,2,2,2,2,2,3,3,3,3,3,3,3,3,3,3,4,4,4,4,4,4,4,4,4,4,4,4,4,4,4};
static constexpr int T3J[35] = {0,0,1,1,0,1,1,2,2,2,0,1,1,2,2,2,3,3,3,3,0,1,1,2,2,2,3,3,3,3,4,4,4,4,4};
static constexpr int T3K[35] = {0,0,0,1,0,0,1,0,1,2,0,0,1,0,1,2,0,1,2,3,0,0,1,0,1,2,0,1,2,3,0,1,2,3,4};

static constexpr int P2[9]  = {0,1,2, 1,3,4, 2,4,5};
static constexpr int P3[27] = {0,1,4, 1,2,5, 4,5,7,
                               1,2,5, 2,3,6, 5,6,8,
                               4,5,7, 5,6,8, 7,8,9};
static constexpr float W2[6]  = {1.f,2.f,2.f,1.f,2.f,1.f};
static constexpr float W3[10] = {1.f,3.f,3.f,1.f,3.f,6.f,3.f,3.f,3.f,1.f};

// moment m -> (rad index, product index). P[0]=1, P[1..3]=d, P[4..9]=q2, P[10..19]=q3
static constexpr int MR[100] = {
    0,1,2,3,4,
    0,0,0,1,1,1,2,2,2,3,3,3,4,4,4,
    0,0,0,0,0,0, 1,1,1,1,1,1, 2,2,2,2,2,2, 3,3,3,3,3,3, 4,4,4,4,4,4,
    0,0,0,0,0,0,0,0,0,0, 1,1,1,1,1,1,1,1,1,1, 2,2,2,2,2,2,2,2,2,2,
    3,3,3,3,3,3,3,3,3,3, 4,4,4,4,4,4,4,4,4,4};
static constexpr int MP[100] = {
    0,0,0,0,0,
    1,2,3,1,2,3,1,2,3,1,2,3,1,2,3,
    4,5,6,7,8,9, 4,5,6,7,8,9, 4,5,6,7,8,9, 4,5,6,7,8,9, 4,5,6,7,8,9,
    10,11,12,13,14,15,16,17,18,19, 10,11,12,13,14,15,16,17,18,19,
    10,11,12,13,14,15,16,17,18,19, 10,11,12,13,14,15,16,17,18,19,
    10,11,12,13,14,15,16,17,18,19};

template<int S>
__device__ __forceinline__ void accum50(float acc[50], const float rad[5], const float P[20])
{
#pragma unroll
    for (int i = 0; i < 50; i++)
        acc[i] += rad[MR[S*50 + i]] * P[MP[S*50 + i]];   // all indices compile-time
}

// ============================ FAST PATH ==================================
// R11: 175.0us. Transposed bins delivered (+coalesced accum reads, edge
// 77->70.5). Pass-1 random-line floor stands (WRITE pinned 64B/record,
// ~1.36TB/s). This round: (1) skip records with dr>=6 entirely -- cut=0 ->
// rad==0 exactly -> contribution is exactly 0.0f; ~2.9% fewer scatters,
// bit-identical output. (2) accum: 2 moment-slices x 8 record-subsets
// (was 4x4) -> each record read 2x not 4x (128->64MB logical), 50
// accumulators/thread (fits 128-VGPR cap at 1024 threads, no spill).

// pass 1: fused edge compute + record scatter (transposed slot layout).
__global__ __launch_bounds__(256) void edge_record_kernel(
    const float* __restrict__ dr_vec, const int* __restrict__ Z,
    const int* __restrict__ nbr, const float* __restrict__ coeffs,
    int* __restrict__ cursor, float* __restrict__ binrec)
{
    int e = blockIdx.x * 256 + threadIdx.x;
    if (e >= NE) return;
    float x = dr_vec[3*e+0], y = dr_vec[3*e+1], z = dr_vec[3*e+2];
    int ai = nbr[e];
    int aj = nbr[NE + e];
    int Zi = Z[ai], Zj = Z[aj];

    float dr  = sqrtf(x*x + y*y + z*z);
    if (dr >= 6.0f) return;            // cut=0 -> rad==0 -> exactly zero contribution

    float inv = 1.0f / (dr + 1e-5f);
    float d0 = x*inv, d1 = y*inv, d2 = z*inv;

    const float PI_F = 3.14159265358979323846f;
    const float betta = 49.0f / 36.0f;
    const float rad_norm = 0.89812905f;          // (2*betta/pi)^0.75, folded
    float cut = 0.5f*(cosf(PI_F * dr * (1.0f/6.0f)) + 1.0f);
    float scale = cut * 0.3779644730092272272f * rad_norm;   // cut/sqrt(7)*norm

    float basis[NB];
#pragma unroll
    for (int b = 0; b < NB; b++) {
        float t = dr - (float)b;
        basis[b] = expf(-betta * t * t);
    }

    const float* cp = coeffs + ((size_t)(Zi*NS + Zj)) * (NR*NB);
    float rad[NR];
#pragma unroll
    for (int r = 0; r < NR; r++) {
        float s = 0.f;
#pragma unroll
        for (int b = 0; b < NB; b++) s += basis[b] * cp[r*NB + b];
        rad[r] = s * scale;
    }

    int pos = __hip_atomic_fetch_add(&cursor[aj], 1, __ATOMIC_RELAXED, __HIP_MEMORY_SCOPE_AGENT);
    if (pos < CAPR) {
        // transposed: row = record index, col = atom -> accum reads coalesce
        float4* rp = (float4*)(binrec + ((size_t)pos * NA + aj) * 8);
        rp[0] = make_float4(rad[0], rad[1], rad[2], rad[3]);
        rp[1] = make_float4(rad[4], d0, d1, d2);
    }
}

// pass 2: accumulate + contract. 1024 threads = 16 waves:
// wave = (sub, slice): slice in {0,1} owns 50 moments (wave-uniform,
// compile-time regs), sub in 0..7 strides records by 8. Transposed bins:
// lane=atom, record p at (p*NA+a)*32B -> 64 lanes = dense 2KB span.
__global__ __launch_bounds__(1024) void accum_contract_kernel(
    const int* __restrict__ cursor, const float* __restrict__ binrec,
    float* __restrict__ out)
{
    __shared__ float lds[CHUNK * MPAD];
    int bl  = blockIdx.x * CHUNK;
    int nat = min(CHUNK, NA - bl);

    int wave  = threadIdx.x >> 6;     // 0..15
    int lane  = threadIdx.x & 63;     // local atom
    int slice = wave & 1;             // moment slice (50 moments)
    int sub   = wave >> 1;            // record subset (stride 8)

    int a = bl + lane;
    int n = (a < NA) ? min(cursor[a], CAPR) : 0;

    float acc[50];
#pragma unroll
    for (int i = 0; i < 50; i++) acc[i] = 0.f;

    const float* bp = binrec + (size_t)a * 8;   // column base for this atom
    for (int p = sub; p < n; p += 8) {
        const float4* rp = (const float4*)(bp + (size_t)p * NA * 8);
        float4 r0 = rp[0], r1 = rp[1];
        float rad[5] = {r0.x, r0.y, r0.z, r0.w, r1.x};
        float d0 = r1.y, d1 = r1.z, d2 = r1.w;

        float P[20];
        P[0] = 1.f; P[1] = d0; P[2] = d1; P[3] = d2;
        P[4] = d0*d0; P[5] = d1*d0; P[6] = d2*d0;
        P[7] = d1*d1; P[8] = d2*d1; P[9] = d2*d2;
        P[10] = d0*P[4]; P[11] = d1*P[4]; P[12] = d0*P[7]; P[13] = d1*P[7];
        P[14] = d2*P[4]; P[15] = d2*P[5]; P[16] = d2*P[7]; P[17] = d0*P[9];
        P[18] = d1*P[9]; P[19] = d2*P[9];

        if (slice == 0) accum50<0>(acc, rad, P);   // wave-uniform branch
        else            accum50<1>(acc, rad, P);
    }

    // merge the 8 record-subsets: ordered rounds, slices disjoint per round
    float* dst = &lds[lane * MPAD + slice * 50];
    for (int s = 0; s < 8; s++) {
        if (sub == s) {
            if (s == 0) {
#pragma unroll
                for (int i = 0; i < 50; i++) dst[i] = acc[i];
            } else {
#pragma unroll
                for (int i = 0; i < 50; i++) dst[i] += acc[i];
            }
        }
        __syncthreads();
    }

    // ---- contract phase: lanes = atoms, 16 waves split the 360 columns ----
    int a2 = bl + lane;
    bool valid = (lane < nat);
    int mb = lane * MPAD;

#define ML(o) lds[mb + (o)]

    for (int cc = wave; cc < 360; cc += 16) {
        if (!valid) continue;
        float v; int dest;

        if (cc < 5) {
            v = ML(cc);
            dest = a2 * OC + cc;
        } else if (cc < 20) {
            int l = cc - 5;
            int r = T2I[l], s = T2J[l];
            float acc2 = 0.f;
#pragma unroll
            for (int i = 0; i < 3; i++) acc2 += ML(5 + r*3 + i) * ML(5 + s*3 + i);
            v = acc2;
            int f = l * NA + a2; int aa = f / 15; dest = aa * OC + 5 + (f - aa*15);
        } else if (cc < 35) {
            int l = cc - 20;
            int r = T2I[l], s = T2J[l];
            float acc2 = 0.f;
#pragma unroll
            for (int p2 = 0; p2 < 6; p2++) acc2 += W2[p2] * ML(20 + r*6 + p2) * ML(20 + s*6 + p2);
            v = acc2;
            int f = l * NA + a2; int aa = f / 15; dest = aa * OC + 20 + (f - aa*15);
        } else if (cc < 50) {
            int l = cc - 35;
            int r = T2I[l], s = T2J[l];
            float acc2 = 0.f;
#pragma unroll
            for (int p2 = 0; p2 < 10; p2++) acc2 += W3[p2] * ML(50 + r*10 + p2) * ML(50 + s*10 + p2);
            v = acc2;
            int f = l * NA + a2; int aa = f / 15; dest = aa * OC + 35 + (f - aa*15);
        } else if (cc < 85) {
            int l = cc - 50;
            int r = T3I[l], s = T3J[l], t = T3K[l];
            float R[6], S[6], T[6];
#pragma unroll
            for (int p2 = 0; p2 < 6; p2++) { R[p2]=ML(20+r*6+p2); S[p2]=ML(20+s*6+p2); T[p2]=ML(20+t*6+p2); }
            float acc2 = 0.f;
#pragma unroll
            for (int i = 0; i < 3; i++)
#pragma unroll
            for (int j = 0; j < 3; j++)
#pragma unroll
            for (int k = 0; k < 3; k++)
                acc2 += R[P2[i*3+j]] * S[P2[i*3+k]] * T[P2[j*3+k]];
            v = acc2;
            int f = l * NA + a2; int aa = f / 35; dest = aa * OC + 50 + (f - aa*35);
        } else if (cc < 160) {
            int l = cc - 85;
            int p2 = l / 5, t = l - p2*5;
            int r = T2I[p2], s = T2J[p2];
            float T[6];
#pragma unroll
            for (int q = 0; q < 6; q++) T[q] = ML(20 + t*6 + q);
            float acc2 = 0.f;
#pragma unroll
            for (int i = 0; i < 3; i++)
#pragma unroll
            for (int j = 0; j < 3; j++)
                acc2 += ML(5 + r*3 + i) * ML(5 + s*3 + j) * T[P2[i*3+j]];
            v = acc2;
            int f = l * NA + a2; int aa = f / 75; dest = aa * OC + 85 + (f - aa*75);
        } else if (cc < 235) {
            int l = cc - 160;
            int p2 = l / 5, t = l - p2*5;
            int r = T2I[p2], s = T2J[p2];
            float R[10], S[10], T[6];
#pragma unroll
            for (int q = 0; q < 10; q++) { R[q]=ML(50+r*10+q); S[q]=ML(50+s*10+q); }
#pragma unroll
            for (int q = 0; q < 6;  q++) T[q] = ML(20 + t*6 + q);
            float acc2 = 0.f;
#pragma unroll
            for (int k = 0; k < 3; k++)
#pragma unroll
            for (int l2 = 0; l2 < 3; l2++) {
                float inner = 0.f;
#pragma unroll
                for (int i = 0; i < 3; i++)
#pragma unroll
                for (int j = 0; j < 3; j++)
                    inner += R[P3[(i*3+j)*3+k]] * S[P3[(i*3+j)*3+l2]];
                acc2 += inner * T[P2[k*3+l2]];
            }
            v = acc2;
            int f = l * NA + a2; int aa = f / 75; dest = aa * OC + 160 + (f - aa*75);
        } else {
            int l = cc - 235;
            int r = l / 25; int rem = l - r*25; int s = rem / 5; int t = rem - s*5;
            float R[10], S[6], T1[3];
#pragma unroll
            for (int q = 0; q < 10; q++) R[q] = ML(50 + r*10 + q);
#pragma unroll
            for (int q = 0; q < 6;  q++) S[q] = ML(20 + s*6 + q);
#pragma unroll
            for (int q = 0; q < 3;  q++) T1[q] = ML(5 + t*3 + q);
            float acc2 = 0.f;
#pragma unroll
            for (int i = 0; i < 3; i++)
#pragma unroll
            for (int j = 0; j < 3; j++)
#pragma unroll
            for (int k = 0; k < 3; k++)
                acc2 += R[P3[(i*3+j)*3+k]] * S[P2[i*3+j]] * T1[k];
            v = acc2;
            int f = l * NA + a2; int aa = f / 125; dest = aa * OC + 235 + (f - aa*125);
        }
        out[dest] = v;
    }
#undef ML
}

// ========================= FALLBACK PATH =======================
__global__ __launch_bounds__(256) void scatter_kernel(
    const int* __restrict__ nbr, int* __restrict__ cursor, int* __restrict__ bins)
{
    int e = blockIdx.x * 256 + threadIdx.x;
    if (e >= NE) return;
    int aj = nbr[NE + e];
    int pos = __hip_atomic_fetch_add(&cursor[aj], 1, __ATOMIC_RELAXED, __HIP_MEMORY_SCOPE_AGENT);
    if (pos < CAPI) bins[(size_t)aj * CAPI + pos] = e;
}

__global__ __launch_bounds__(256) void accum_kernel(
    const float* __restrict__ dr_vec, const int* __restrict__ Z,
    const int* __restrict__ nbr, const float* __restrict__ coeffs,
    const int* __restrict__ cursor, const int* __restrict__ bins,
    float* __restrict__ Mu)
{
    __shared__ float red[32 * MUS];
    int t   = blockIdx.x * 256 + threadIdx.x;
    int a   = t >> 3;
    int sub = t & 7;
    int al  = threadIdx.x >> 3;
    int n   = (a < NA) ? min(cursor[a], CAPI) : 0;
    int Zj  = (a < NA) ? Z[a] : 0;

    float acc[MUS];
#pragma unroll
    for (int i = 0; i < MUS; i++) acc[i] = 0.f;

    const int* mybin = bins + (size_t)a * CAPI;
    const float PI_F = 3.14159265358979323846f;
    const float betta = 49.0f / 36.0f;
    float rad_norm = 0.89812905f;

    for (int p = sub; p < n; p += 8) {
        int e = mybin[p];
        float x = dr_vec[3*e+0], y = dr_vec[3*e+1], z = dr_vec[3*e+2];
        int Zi = Z[nbr[e]];

        float dr  = sqrtf(x*x + y*y + z*z);
        float inv = 1.0f / (dr + 1e-5f);
        float d0 = x*inv, d1 = y*inv, d2 = z*inv;

        float cut = (dr < 6.0f) ? 0.5f*(cosf(PI_F * dr * (1.0f/6.0f)) + 1.0f) : 0.0f;
        float scale = cut * 0.3779644730092272272f * rad_norm;

        float basis[NB];
#pragma unroll
        for (int b = 0; b < NB; b++) {
            float tt = dr - (float)b;
            basis[b] = expf(-betta * tt * tt);
        }

        const float* cp = coeffs + ((size_t)(Zi*NS + Zj)) * (NR*NB);
        float rad[NR];
#pragma unroll
        for (int r = 0; r < NR; r++) {
            float s = 0.f;
#pragma unroll
            for (int b = 0; b < NB; b++) s += basis[b] * cp[r*NB + b];
            rad[r] = s * scale;
        }

        float q2[6] = {d0*d0, d1*d0, d2*d0, d1*d1, d2*d1, d2*d2};
        float q3[10] = {d0*q2[0], d1*q2[0], d0*q2[3], d1*q2[3], d2*q2[0],
                        d2*q2[1], d2*q2[3], d0*q2[5], d1*q2[5], d2*q2[5]};

#pragma unroll
        for (int r = 0; r < NR; r++) {
            float rv = rad[r];
            acc[r] += rv;
            acc[5 + r*3 + 0] += rv*d0;
            acc[5 + r*3 + 1] += rv*d1;
            acc[5 + r*3 + 2] += rv*d2;
#pragma unroll
            for (int q = 0; q < 6; q++)  acc[20 + r*6  + q] += rv*q2[q];
#pragma unroll
            for (int q = 0; q < 10; q++) acc[50 + r*10 + q] += rv*q3[q];
        }
    }

#pragma unroll
    for (int i = 0; i < MUS; i++) {
        float v = acc[i];
        v += __shfl_xor(v, 1, 64);
        v += __shfl_xor(v, 2, 64);
        v += __shfl_xor(v, 4, 64);
        if (sub == 0) red[al * MUS + i] = v;
    }
    __syncthreads();

    for (int u = threadIdx.x; u < 32 * MUS; u += 256) {
        int ga = blockIdx.x * 32 + u / MUS;
        if (ga < NA) Mu[(size_t)ga * MUS + (u - (u / MUS) * MUS)] = red[u];
    }
}

__global__ __launch_bounds__(256) void contract_kernel(
    const float* __restrict__ Mu, float* __restrict__ out)
{
    __shared__ float lds[64 * MPAD];
    int base = blockIdx.x * 64;
    int nat  = min(64, NA - base);

    for (int t = threadIdx.x; t < nat * MUS; t += 256) {
        int al = t / MUS, off = t - al * MUS;
        lds[al * MPAD + off] = Mu[(size_t)base * MUS + t];
    }
    __syncthreads();

    int wave = threadIdx.x >> 6, lane = threadIdx.x & 63;
    int a2 = base + lane;
    bool valid = (lane < nat);
    int mb = lane * MPAD;

#define ML(o) lds[mb + (o)]

    for (int cc = wave; cc < 360; cc += 4) {
        if (!valid) continue;
        float v; int dest;

        if (cc < 5) {
            v = ML(cc);
            dest = a2 * OC + cc;
        } else if (cc < 20) {
            int l = cc - 5;
            int r = T2I[l], s = T2J[l];
            float acc = 0.f;
#pragma unroll
            for (int i = 0; i < 3; i++) acc += ML(5 + r*3 + i) * ML(5 + s*3 + i);
            v = acc;
            int f = l * NA + a2; int aa = f / 15; dest = aa * OC + 5 + (f - aa*15);
        } else if (cc < 35) {
            int l = cc - 20;
            int r = T2I[l], s = T2J[l];
            float acc = 0.f;
#pragma unroll
            for (int p = 0; p < 6; p++) acc += W2[p] * ML(20 + r*6 + p) * ML(20 + s*6 + p);
            v = acc;
            int f = l * NA + a2; int aa = f / 15; dest = aa * OC + 20 + (f - aa*15);
        } else if (cc < 50) {
            int l = cc - 35;
            int r = T2I[l], s = T2J[l];
            float acc = 0.f;
#pragma unroll
            for (int p = 0; p < 10; p++) acc += W3[p] * ML(50 + r*10 + p) * ML(50 + s*10 + p);
            v = acc;
            int f = l * NA + a2; int aa = f / 15; dest = aa * OC + 35 + (f - aa*15);
        } else if (cc < 85) {
            int l = cc - 50;
            int r = T3I[l], s = T3J[l], t = T3K[l];
            float R[6], S[6], T[6];
#pragma unroll
            for (int p = 0; p < 6; p++) { R[p]=ML(20+r*6+p); S[p]=ML(20+s*6+p); T[p]=ML(20+t*6+p); }
            float acc = 0.f;
#pragma unroll
            for (int i = 0; i < 3; i++)
#pragma unroll
            for (int j = 0; j < 3; j++)
#pragma unroll
            for (int k = 0; k < 3; k++)
                acc += R[P2[i*3+j]] * S[P2[i*3+k]] * T[P2[j*3+k]];
            v = acc;
            int f = l * NA + a2; int aa = f / 35; dest = aa * OC + 50 + (f - aa*35);
        } else if (cc < 160) {
            int l = cc - 85;
            int p = l / 5, t = l - p*5;
            int r = T2I[p], s = T2J[p];
            float T[6];
#pragma unroll
            for (int q = 0; q < 6; q++) T[q] = ML(20 + t*6 + q);
            float acc = 0.f;
#pragma unroll
            for (int i = 0; i < 3; i++)
#pragma unroll
            for (int j = 0; j < 3; j++)
                acc += ML(5 + r*3 + i) * ML(5 + s*3 + j) * T[P2[i*3+j]];
            v = acc;
            int f = l * NA + a2; int aa = f / 75; dest = aa * OC + 85 + (f - aa*75);
        } else if (cc < 235) {
            int l = cc - 160;
            int p = l / 5, t = l - p*5;
            int r = T2I[p], s = T2J[p];
            float R[10], S[10], T[6];
#pragma unroll
            for (int q = 0; q < 10; q++) { R[q]=ML(50+r*10+q); S[q]=ML(50+s*10+q); }
#pragma unroll
            for (int q = 0; q < 6;  q++) T[q] = ML(20 + t*6 + q);
            float acc = 0.f;
#pragma unroll
            for (int k = 0; k < 3; k++)
#pragma unroll
            for (int l2 = 0; l2 < 3; l2++) {
                float inner = 0.f;
#pragma unroll
                for (int i = 0; i < 3; i++)
#pragma unroll
                for (int j = 0; j < 3; j++)
                    inner += R[P3[(i*3+j)*3+k]] * S[P3[(i*3+j)*3+l2]];
                acc += inner * T[P2[k*3+l2]];
            }
            v = acc;
            int f = l * NA + a2; int aa = f / 75; dest = aa * OC + 160 + (f - aa*75);
        } else {
            int l = cc - 235;
            int r = l / 25; int rem = l - r*25; int s = rem / 5; int t = rem - s*5;
            float R[10], S[6], T1[3];
#pragma unroll
            for (int q = 0; q < 10; q++) R[q] = ML(50 + r*10 + q);
#pragma unroll
            for (int q = 0; q < 6;  q++) S[q] = ML(20 + s*6 + q);
#pragma unroll
            for (int q = 0; q < 3;  q++) T1[q] = ML(5 + t*3 + q);
            float acc = 0.f;
#pragma unroll
            for (int i = 0; i < 3; i++)
#pragma unroll
            for (int j = 0; j < 3; j++)
#pragma unroll
            for (int k = 0; k < 3; k++)
                acc += R[P3[(i*3+j)*3+k]] * S[P2[i*3+j]] * T1[k];
            v = acc;
            int f = l * NA + a2; int aa = f / 125; dest = aa * OC + 235 + (f - aa*125);
        }
        out[dest] = v;
    }
#undef ML
}

extern "C" void kernel_launch(void* const* d_in, const int* in_sizes, int n_in,
                              void* d_out, int out_size, void* d_ws, size_t ws_size,
                              hipStream_t stream) {
    const float* dr_vec = (const float*)d_in[0];
    const int*   Z      = (const int*)d_in[1];
    const int*   nbr    = (const int*)d_in[2];
    const float* coeffs = (const float*)d_in[3];
    float* out = (float*)d_out;

    // fast path: binrec FIRST (76.8MB, 64B-aligned), then cursor[NA]
    size_t binrec_fl = (size_t)NA * CAPR * 8;          // floats
    size_t need_fast = binrec_fl * sizeof(float) + (size_t)NA * sizeof(int);

    if (ws_size >= need_fast) {
        float* binrec = (float*)d_ws;
        int*   cursor = (int*)(binrec + binrec_fl);
        hipMemsetAsync(cursor, 0, (size_t)NA * sizeof(int), stream);
        edge_record_kernel<<<(NE + 255)/256, 256, 0, stream>>>(dr_vec, Z, nbr, coeffs, cursor, binrec);
        accum_contract_kernel<<<(NA + CHUNK - 1)/CHUNK, 1024, 0, stream>>>(cursor, binrec, out);
    } else {
        // fallback: cursor[NA] | bins[NA*CAPI] | Mu[NA*MUS] (~21.3 MB)
        int*   cursor = (int*)d_ws;
        int*   bins   = cursor + NA;
        float* Mu     = (float*)(bins + (size_t)NA * CAPI);
        hipMemsetAsync(cursor, 0, (size_t)NA * sizeof(int), stream);
        scatter_kernel<<<(NE + 255)/256, 256, 0, stream>>>(nbr, cursor, bins);
        accum_kernel<<<(NA*8 + 255)/256, 256, 0, stream>>>(dr_vec, Z, nbr, coeffs, cursor, bins, Mu);
        contract_kernel<<<(NA + 63)/64, 256, 0, stream>>>(Mu, out);
    }
}

// Round 13
// 184.729 us; speedup vs baseline: 1.0332x; 1.0332x over previous
//
#include <hip/hip_runtime.h>
#include <math.h>

#define NR 5
#define NB 7
#define NS 119
#define NA 25000
#define NE 1000000
#define OC 360           // output columns per atom
#define MUS 100          // unique moment floats per atom
#define CAPR 96          // record bin capacity (lambda=40, max ~68, overflow ~1e-15)
#define CAPI 112         // id bin capacity (fallback path)
#define CHUNK 64         // atoms per accum/contract block
#define MPAD 101         // LDS stride: gcd(101,32)=1 -> conflict-free

// tril index tables (wave-uniform index -> scalar loads)
static constexpr int T2I[15] = {0,1,1,2,2,2,3,3,3,3,4,4,4,4,4};
static constexpr int T2J[15] = {0,0,1,0,1,2,0,1,2,3,0,1,2,3,4};
static constexpr int T3I[35] = {0,1,1,1,2,2,2,2,2,2,3,3,3,3,3,3,3,3,3,3,4,4,4,4,4,4,4,4,4,4,4,4,4,4,4};
static constexpr int T3J[35] = {0,0,1,1,0,1,1,2,2,2,0,1,1,2,2,2,3,3,3,3,0,1,1,2,2,2,3,3,3,3,4,4,4,4,4};
static constexpr int T3K[35] = {0,0,0,1,0,0,1,0,1,2,0,0,1,0,1,2,0,1,2,3,0,0,1,0,1,2,0,1,2,3,0,1,2,3,4};

static constexpr int P2[9]  = {0,1,2, 1,3,4, 2,4,5};
static constexpr int P3[27] = {0,1,4, 1,2,5, 4,5,7,
                               1,2,5, 2,3,6, 5,6,8,
                               4,5,7, 5,6,8, 7,8,9};
static constexpr float W2[6]  = {1.f,2.f,2.f,1.f,2.f,1.f};
static constexpr float W3[10] = {1.f,3.f,3.f,1.f,3.f,6.f,3.f,3.f,3.f,1.f};

// moment m -> (rad index, product index). P[0]=1, P[1..3]=d, P[4..9]=q2, P[10..19]=q3
static constexpr int MR[100] = {
    0,1,2,3,4,
    0,0,0,1,1,1,2,2,2,3,3,3,4,4,4,
    0,0,0,0,0,0, 1,1,1,1,1,1, 2,2,2,2,2,2, 3,3,3,3,3,3, 4,4,4,4,4,4,
    0,0,0,0,0,0,0,0,0,0, 1,1,1,1,1,1,1,1,1,1, 2,2,2,2,2,2,2,2,2,2,
    3,3,3,3,3,3,3,3,3,3, 4,4,4,4,4,4,4,4,4,4};
static constexpr int MP[100] = {
    0,0,0,0,0,
    1,2,3,1,2,3,1,2,3,1,2,3,1,2,3,
    4,5,6,7,8,9, 4,5,6,7,8,9, 4,5,6,7,8,9, 4,5,6,7,8,9, 4,5,6,7,8,9,
    10,11,12,13,14,15,16,17,18,19, 10,11,12,13,14,15,16,17,18,19,
    10,11,12,13,14,15,16,17,18,19, 10,11,12,13,14,15,16,17,18,19,
    10,11,12,13,14,15,16,17,18,19};

template<int S>
__device__ __forceinline__ void accum25(float acc[25], const float rad[5], const float P[20])
{
#pragma unroll
    for (int i = 0; i < 25; i++)
        acc[i] += rad[MR[S*25 + i]] * P[MP[S*25 + i]];   // all indices compile-time
}

// ============================ FAST PATH ==================================
// R12 post-mortem: 2x8 slicing (acc[50]) regressed +16us -- register
// pressure at the 128-VGPR/1024-thread cap + 8 barrier-rounds; read
// redundancy was NOT the bottleneck. REVERT accum to R11's proven 4x4
// (acc[25], 4-round merge, measured inside 175.0us). KEEP the dr>=6 skip
// (verified -2MB WRITE, bit-exact: cut=0 -> rad==0 -> zero contribution).

// pass 1: fused edge compute + record scatter (transposed slot layout).
__global__ __launch_bounds__(256) void edge_record_kernel(
    const float* __restrict__ dr_vec, const int* __restrict__ Z,
    const int* __restrict__ nbr, const float* __restrict__ coeffs,
    int* __restrict__ cursor, float* __restrict__ binrec)
{
    int e = blockIdx.x * 256 + threadIdx.x;
    if (e >= NE) return;
    float x = dr_vec[3*e+0], y = dr_vec[3*e+1], z = dr_vec[3*e+2];
    int ai = nbr[e];
    int aj = nbr[NE + e];
    int Zi = Z[ai], Zj = Z[aj];

    float dr  = sqrtf(x*x + y*y + z*z);
    if (dr >= 6.0f) return;            // cut=0 -> rad==0 -> exactly zero contribution

    float inv = 1.0f / (dr + 1e-5f);
    float d0 = x*inv, d1 = y*inv, d2 = z*inv;

    const float PI_F = 3.14159265358979323846f;
    const float betta = 49.0f / 36.0f;
    const float rad_norm = 0.89812905f;          // (2*betta/pi)^0.75, folded
    float cut = 0.5f*(cosf(PI_F * dr * (1.0f/6.0f)) + 1.0f);
    float scale = cut * 0.3779644730092272272f * rad_norm;   // cut/sqrt(7)*norm

    float basis[NB];
#pragma unroll
    for (int b = 0; b < NB; b++) {
        float t = dr - (float)b;
        basis[b] = expf(-betta * t * t);
    }

    const float* cp = coeffs + ((size_t)(Zi*NS + Zj)) * (NR*NB);
    float rad[NR];
#pragma unroll
    for (int r = 0; r < NR; r++) {
        float s = 0.f;
#pragma unroll
        for (int b = 0; b < NB; b++) s += basis[b] * cp[r*NB + b];
        rad[r] = s * scale;
    }

    int pos = __hip_atomic_fetch_add(&cursor[aj], 1, __ATOMIC_RELAXED, __HIP_MEMORY_SCOPE_AGENT);
    if (pos < CAPR) {
        // transposed: row = record index, col = atom -> accum reads coalesce
        float4* rp = (float4*)(binrec + ((size_t)pos * NA + aj) * 8);
        rp[0] = make_float4(rad[0], rad[1], rad[2], rad[3]);
        rp[1] = make_float4(rad[4], d0, d1, d2);
    }
}

// pass 2: accumulate + contract. 1024 threads = 16 waves:
// wave = (sub, slice): slice owns 25 moments (wave-uniform, constant regs),
// sub strides records by 4. Transposed bins: lane=atom, record p read at
// (p*NA + a)*32B -> 64 lanes cover one dense 2KB span (coalesced).
__global__ __launch_bounds__(1024) void accum_contract_kernel(
    const int* __restrict__ cursor, const float* __restrict__ binrec,
    float* __restrict__ out)
{
    __shared__ float lds[CHUNK * MPAD];
    int bl  = blockIdx.x * CHUNK;
    int nat = min(CHUNK, NA - bl);

    int wave  = threadIdx.x >> 6;     // 0..15
    int lane  = threadIdx.x & 63;     // local atom
    int slice = wave & 3;             // moment slice (25 moments)
    int sub   = wave >> 2;            // record subset (stride 4)

    int a = bl + lane;
    int n = (a < NA) ? min(cursor[a], CAPR) : 0;

    float acc[25];
#pragma unroll
    for (int i = 0; i < 25; i++) acc[i] = 0.f;

    const float* bp = binrec + (size_t)a * 8;   // column base for this atom
    for (int p = sub; p < n; p += 4) {
        const float4* rp = (const float4*)(bp + (size_t)p * NA * 8);
        float4 r0 = rp[0], r1 = rp[1];
        float rad[5] = {r0.x, r0.y, r0.z, r0.w, r1.x};
        float d0 = r1.y, d1 = r1.z, d2 = r1.w;

        float P[20];
        P[0] = 1.f; P[1] = d0; P[2] = d1; P[3] = d2;
        P[4] = d0*d0; P[5] = d1*d0; P[6] = d2*d0;
        P[7] = d1*d1; P[8] = d2*d1; P[9] = d2*d2;
        P[10] = d0*P[4]; P[11] = d1*P[4]; P[12] = d0*P[7]; P[13] = d1*P[7];
        P[14] = d2*P[4]; P[15] = d2*P[5]; P[16] = d2*P[7]; P[17] = d0*P[9];
        P[18] = d1*P[9]; P[19] = d2*P[9];

        switch (slice) {              // wave-uniform: no divergence
            case 0: accum25<0>(acc, rad, P); break;
            case 1: accum25<1>(acc, rad, P); break;
            case 2: accum25<2>(acc, rad, P); break;
            default: accum25<3>(acc, rad, P); break;
        }
    }

    // merge the 4 record-subsets: ordered rounds, slices disjoint per round
    float* dst = &lds[lane * MPAD + slice * 25];
    for (int s = 0; s < 4; s++) {
        if (sub == s) {
            if (s == 0) {
#pragma unroll
                for (int i = 0; i < 25; i++) dst[i] = acc[i];
            } else {
#pragma unroll
                for (int i = 0; i < 25; i++) dst[i] += acc[i];
            }
        }
        __syncthreads();
    }

    // ---- contract phase: lanes = atoms, 16 waves split the 360 columns ----
    int a2 = bl + lane;
    bool valid = (lane < nat);
    int mb = lane * MPAD;

#define ML(o) lds[mb + (o)]

    for (int cc = wave; cc < 360; cc += 16) {
        if (!valid) continue;
        float v; int dest;

        if (cc < 5) {
            v = ML(cc);
            dest = a2 * OC + cc;
        } else if (cc < 20) {
            int l = cc - 5;
            int r = T2I[l], s = T2J[l];
            float acc2 = 0.f;
#pragma unroll
            for (int i = 0; i < 3; i++) acc2 += ML(5 + r*3 + i) * ML(5 + s*3 + i);
            v = acc2;
            int f = l * NA + a2; int aa = f / 15; dest = aa * OC + 5 + (f - aa*15);
        } else if (cc < 35) {
            int l = cc - 20;
            int r = T2I[l], s = T2J[l];
            float acc2 = 0.f;
#pragma unroll
            for (int p2 = 0; p2 < 6; p2++) acc2 += W2[p2] * ML(20 + r*6 + p2) * ML(20 + s*6 + p2);
            v = acc2;
            int f = l * NA + a2; int aa = f / 15; dest = aa * OC + 20 + (f - aa*15);
        } else if (cc < 50) {
            int l = cc - 35;
            int r = T2I[l], s = T2J[l];
            float acc2 = 0.f;
#pragma unroll
            for (int p2 = 0; p2 < 10; p2++) acc2 += W3[p2] * ML(50 + r*10 + p2) * ML(50 + s*10 + p2);
            v = acc2;
            int f = l * NA + a2; int aa = f / 15; dest = aa * OC + 35 + (f - aa*15);
        } else if (cc < 85) {
            int l = cc - 50;
            int r = T3I[l], s = T3J[l], t = T3K[l];
            float R[6], S[6], T[6];
#pragma unroll
            for (int p2 = 0; p2 < 6; p2++) { R[p2]=ML(20+r*6+p2); S[p2]=ML(20+s*6+p2); T[p2]=ML(20+t*6+p2); }
            float acc2 = 0.f;
#pragma unroll
            for (int i = 0; i < 3; i++)
#pragma unroll
            for (int j = 0; j < 3; j++)
#pragma unroll
            for (int k = 0; k < 3; k++)
                acc2 += R[P2[i*3+j]] * S[P2[i*3+k]] * T[P2[j*3+k]];
            v = acc2;
            int f = l * NA + a2; int aa = f / 35; dest = aa * OC + 50 + (f - aa*35);
        } else if (cc < 160) {
            int l = cc - 85;
            int p2 = l / 5, t = l - p2*5;
            int r = T2I[p2], s = T2J[p2];
            float T[6];
#pragma unroll
            for (int q = 0; q < 6; q++) T[q] = ML(20 + t*6 + q);
            float acc2 = 0.f;
#pragma unroll
            for (int i = 0; i < 3; i++)
#pragma unroll
            for (int j = 0; j < 3; j++)
                acc2 += ML(5 + r*3 + i) * ML(5 + s*3 + j) * T[P2[i*3+j]];
            v = acc2;
            int f = l * NA + a2; int aa = f / 75; dest = aa * OC + 85 + (f - aa*75);
        } else if (cc < 235) {
            int l = cc - 160;
            int p2 = l / 5, t = l - p2*5;
            int r = T2I[p2], s = T2J[p2];
            float R[10], S[10], T[6];
#pragma unroll
            for (int q = 0; q < 10; q++) { R[q]=ML(50+r*10+q); S[q]=ML(50+s*10+q); }
#pragma unroll
            for (int q = 0; q < 6;  q++) T[q] = ML(20 + t*6 + q);
            float acc2 = 0.f;
#pragma unroll
            for (int k = 0; k < 3; k++)
#pragma unroll
            for (int l2 = 0; l2 < 3; l2++) {
                float inner = 0.f;
#pragma unroll
                for (int i = 0; i < 3; i++)
#pragma unroll
                for (int j = 0; j < 3; j++)
                    inner += R[P3[(i*3+j)*3+k]] * S[P3[(i*3+j)*3+l2]];
                acc2 += inner * T[P2[k*3+l2]];
            }
            v = acc2;
            int f = l * NA + a2; int aa = f / 75; dest = aa * OC + 160 + (f - aa*75);
        } else {
            int l = cc - 235;
            int r = l / 25; int rem = l - r*25; int s = rem / 5; int t = rem - s*5;
            float R[10], S[6], T1[3];
#pragma unroll
            for (int q = 0; q < 10; q++) R[q] = ML(50 + r*10 + q);
#pragma unroll
            for (int q = 0; q < 6;  q++) S[q] = ML(20 + s*6 + q);
#pragma unroll
            for (int q = 0; q < 3;  q++) T1[q] = ML(5 + t*3 + q);
            float acc2 = 0.f;
#pragma unroll
            for (int i = 0; i < 3; i++)
#pragma unroll
            for (int j = 0; j < 3; j++)
#pragma unroll
            for (int k = 0; k < 3; k++)
                acc2 += R[P3[(i*3+j)*3+k]] * S[P2[i*3+j]] * T1[k];
            v = acc2;
            int f = l * NA + a2; int aa = f / 125; dest = aa * OC + 235 + (f - aa*125);
        }
        out[dest] = v;
    }
#undef ML
}

// ========================= FALLBACK PATH =======================
__global__ __launch_bounds__(256) void scatter_kernel(
    const int* __restrict__ nbr, int* __restrict__ cursor, int* __restrict__ bins)
{
    int e = blockIdx.x * 256 + threadIdx.x;
    if (e >= NE) return;
    int aj = nbr[NE + e];
    int pos = __hip_atomic_fetch_add(&cursor[aj], 1, __ATOMIC_RELAXED, __HIP_MEMORY_SCOPE_AGENT);
    if (pos < CAPI) bins[(size_t)aj * CAPI + pos] = e;
}

__global__ __launch_bounds__(256) void accum_kernel(
    const float* __restrict__ dr_vec, const int* __restrict__ Z,
    const int* __restrict__ nbr, const float* __restrict__ coeffs,
    const int* __restrict__ cursor, const int* __restrict__ bins,
    float* __restrict__ Mu)
{
    __shared__ float red[32 * MUS];
    int t   = blockIdx.x * 256 + threadIdx.x;
    int a   = t >> 3;
    int sub = t & 7;
    int al  = threadIdx.x >> 3;
    int n   = (a < NA) ? min(cursor[a], CAPI) : 0;
    int Zj  = (a < NA) ? Z[a] : 0;

    float acc[MUS];
#pragma unroll
    for (int i = 0; i < MUS; i++) acc[i] = 0.f;

    const int* mybin = bins + (size_t)a * CAPI;
    const float PI_F = 3.14159265358979323846f;
    const float betta = 49.0f / 36.0f;
    float rad_norm = 0.89812905f;

    for (int p = sub; p < n; p += 8) {
        int e = mybin[p];
        float x = dr_vec[3*e+0], y = dr_vec[3*e+1], z = dr_vec[3*e+2];
        int Zi = Z[nbr[e]];

        float dr  = sqrtf(x*x + y*y + z*z);
        float inv = 1.0f / (dr + 1e-5f);
        float d0 = x*inv, d1 = y*inv, d2 = z*inv;

        float cut = (dr < 6.0f) ? 0.5f*(cosf(PI_F * dr * (1.0f/6.0f)) + 1.0f) : 0.0f;
        float scale = cut * 0.3779644730092272272f * rad_norm;

        float basis[NB];
#pragma unroll
        for (int b = 0; b < NB; b++) {
            float tt = dr - (float)b;
            basis[b] = expf(-betta * tt * tt);
        }

        const float* cp = coeffs + ((size_t)(Zi*NS + Zj)) * (NR*NB);
        float rad[NR];
#pragma unroll
        for (int r = 0; r < NR; r++) {
            float s = 0.f;
#pragma unroll
            for (int b = 0; b < NB; b++) s += basis[b] * cp[r*NB + b];
            rad[r] = s * scale;
        }

        float q2[6] = {d0*d0, d1*d0, d2*d0, d1*d1, d2*d1, d2*d2};
        float q3[10] = {d0*q2[0], d1*q2[0], d0*q2[3], d1*q2[3], d2*q2[0],
                        d2*q2[1], d2*q2[3], d0*q2[5], d1*q2[5], d2*q2[5]};

#pragma unroll
        for (int r = 0; r < NR; r++) {
            float rv = rad[r];
            acc[r] += rv;
            acc[5 + r*3 + 0] += rv*d0;
            acc[5 + r*3 + 1] += rv*d1;
            acc[5 + r*3 + 2] += rv*d2;
#pragma unroll
            for (int q = 0; q < 6; q++)  acc[20 + r*6  + q] += rv*q2[q];
#pragma unroll
            for (int q = 0; q < 10; q++) acc[50 + r*10 + q] += rv*q3[q];
        }
    }

#pragma unroll
    for (int i = 0; i < MUS; i++) {
        float v = acc[i];
        v += __shfl_xor(v, 1, 64);
        v += __shfl_xor(v, 2, 64);
        v += __shfl_xor(v, 4, 64);
        if (sub == 0) red[al * MUS + i] = v;
    }
    __syncthreads();

    for (int u = threadIdx.x; u < 32 * MUS; u += 256) {
        int ga = blockIdx.x * 32 + u / MUS;
        if (ga < NA) Mu[(size_t)ga * MUS + (u - (u / MUS) * MUS)] = red[u];
    }
}

__global__ __launch_bounds__(256) void contract_kernel(
    const float* __restrict__ Mu, float* __restrict__ out)
{
    __shared__ float lds[64 * MPAD];
    int base = blockIdx.x * 64;
    int nat  = min(64, NA - base);

    for (int t = threadIdx.x; t < nat * MUS; t += 256) {
        int al = t / MUS, off = t - al * MUS;
        lds[al * MPAD + off] = Mu[(size_t)base * MUS + t];
    }
    __syncthreads();

    int wave = threadIdx.x >> 6, lane = threadIdx.x & 63;
    int a2 = base + lane;
    bool valid = (lane < nat);
    int mb = lane * MPAD;

#define ML(o) lds[mb + (o)]

    for (int cc = wave; cc < 360; cc += 4) {
        if (!valid) continue;
        float v; int dest;

        if (cc < 5) {
            v = ML(cc);
            dest = a2 * OC + cc;
        } else if (cc < 20) {
            int l = cc - 5;
            int r = T2I[l], s = T2J[l];
            float acc = 0.f;
#pragma unroll
            for (int i = 0; i < 3; i++) acc += ML(5 + r*3 + i) * ML(5 + s*3 + i);
            v = acc;
            int f = l * NA + a2; int aa = f / 15; dest = aa * OC + 5 + (f - aa*15);
        } else if (cc < 35) {
            int l = cc - 20;
            int r = T2I[l], s = T2J[l];
            float acc = 0.f;
#pragma unroll
            for (int p = 0; p < 6; p++) acc += W2[p] * ML(20 + r*6 + p) * ML(20 + s*6 + p);
            v = acc;
            int f = l * NA + a2; int aa = f / 15; dest = aa * OC + 20 + (f - aa*15);
        } else if (cc < 50) {
            int l = cc - 35;
            int r = T2I[l], s = T2J[l];
            float acc = 0.f;
#pragma unroll
            for (int p = 0; p < 10; p++) acc += W3[p] * ML(50 + r*10 + p) * ML(50 + s*10 + p);
            v = acc;
            int f = l * NA + a2; int aa = f / 15; dest = aa * OC + 35 + (f - aa*15);
        } else if (cc < 85) {
            int l = cc - 50;
            int r = T3I[l], s = T3J[l], t = T3K[l];
            float R[6], S[6], T[6];
#pragma unroll
            for (int p = 0; p < 6; p++) { R[p]=ML(20+r*6+p); S[p]=ML(20+s*6+p); T[p]=ML(20+t*6+p); }
            float acc = 0.f;
#pragma unroll
            for (int i = 0; i < 3; i++)
#pragma unroll
            for (int j = 0; j < 3; j++)
#pragma unroll
            for (int k = 0; k < 3; k++)
                acc += R[P2[i*3+j]] * S[P2[i*3+k]] * T[P2[j*3+k]];
            v = acc;
            int f = l * NA + a2; int aa = f / 35; dest = aa * OC + 50 + (f - aa*35);
        } else if (cc < 160) {
            int l = cc - 85;
            int p = l / 5, t = l - p*5;
            int r = T2I[p], s = T2J[p];
            float T[6];
#pragma unroll
            for (int q = 0; q < 6; q++) T[q] = ML(20 + t*6 + q);
            float acc = 0.f;
#pragma unroll
            for (int i = 0; i < 3; i++)
#pragma unroll
            for (int j = 0; j < 3; j++)
                acc += ML(5 + r*3 + i) * ML(5 + s*3 + j) * T[P2[i*3+j]];
            v = acc;
            int f = l * NA + a2; int aa = f / 75; dest = aa * OC + 85 + (f - aa*75);
        } else if (cc < 235) {
            int l = cc - 160;
            int p = l / 5, t = l - p*5;
            int r = T2I[p], s = T2J[p];
            float R[10], S[10], T[6];
#pragma unroll
            for (int q = 0; q < 10; q++) { R[q]=ML(50+r*10+q); S[q]=ML(50+s*10+q); }
#pragma unroll
            for (int q = 0; q < 6;  q++) T[q] = ML(20 + t*6 + q);
            float acc = 0.f;
#pragma unroll
            for (int k = 0; k < 3; k++)
#pragma unroll
            for (int l2 = 0; l2 < 3; l2++) {
                float inner = 0.f;
#pragma unroll
                for (int i = 0; i < 3; i++)
#pragma unroll
                for (int j = 0; j < 3; j++)
                    inner += R[P3[(i*3+j)*3+k]] * S[P3[(i*3+j)*3+l2]];
                acc += inner * T[P2[k*3+l2]];
            }
            v = acc;
            int f = l * NA + a2; int aa = f / 75; dest = aa * OC + 160 + (f - aa*75);
        } else {
            int l = cc - 235;
            int r = l / 25; int rem = l - r*25; int s = rem / 5; int t = rem - s*5;
            float R[10], S[6], T1[3];
#pragma unroll
            for (int q = 0; q < 10; q++) R[q] = ML(50 + r*10 + q);
#pragma unroll
            for (int q = 0; q < 6;  q++) S[q] = ML(20 + s*6 + q);
#pragma unroll
            for (int q = 0; q < 3;  q++) T1[q] = ML(5 + t*3 + q);
            float acc = 0.f;
#pragma unroll
            for (int i = 0; i < 3; i++)
#pragma unroll
            for (int j = 0; j < 3; j++)
#pragma unroll
            for (int k = 0; k < 3; k++)
                acc += R[P3[(i*3+j)*3+k]] * S[P2[i*3+j]] * T1[k];
            v = acc;
            int f = l * NA + a2; int aa = f / 125; dest = aa * OC + 235 + (f - aa*125);
        }
        out[dest] = v;
    }
#undef ML
}

extern "C" void kernel_launch(void* const* d_in, const int* in_sizes, int n_in,
                              void* d_out, int out_size, void* d_ws, size_t ws_size,
                              hipStream_t stream) {
    const float* dr_vec = (const float*)d_in[0];
    const int*   Z      = (const int*)d_in[1];
    const int*   nbr    = (const int*)d_in[2];
    const float* coeffs = (const float*)d_in[3];
    float* out = (float*)d_out;

    // fast path: binrec FIRST (76.8MB, 64B-aligned), then cursor[NA]
    size_t binrec_fl = (size_t)NA * CAPR * 8;          // floats
    size_t need_fast = binrec_fl * sizeof(float) + (size_t)NA * sizeof(int);

    if (ws_size >= need_fast) {
        float* binrec = (float*)d_ws;
        int*   cursor = (int*)(binrec + binrec_fl);
        hipMemsetAsync(cursor, 0, (size_t)NA * sizeof(int), stream);
        edge_record_kernel<<<(NE + 255)/256, 256, 0, stream>>>(dr_vec, Z, nbr, coeffs, cursor, binrec);
        accum_contract_kernel<<<(NA + CHUNK - 1)/CHUNK, 1024, 0, stream>>>(cursor, binrec, out);
    } else {
        // fallback: cursor[NA] | bins[NA*CAPI] | Mu[NA*MUS] (~21.3 MB)
        int*   cursor = (int*)d_ws;
        int*   bins   = cursor + NA;
        float* Mu     = (float*)(bins + (size_t)NA * CAPI);
        hipMemsetAsync(cursor, 0, (size_t)NA * sizeof(int), stream);
        scatter_kernel<<<(NE + 255)/256, 256, 0, stream>>>(nbr, cursor, bins);
        accum_kernel<<<(NA*8 + 255)/256, 256, 0, stream>>>(dr_vec, Z, nbr, coeffs, cursor, bins, Mu);
        contract_kernel<<<(NA + 63)/64, 256, 0, stream>>>(Mu, out);
    }
}

// Round 14
// 175.740 us; speedup vs baseline: 1.0860x; 1.0511x over previous
//
#include <hip/hip_runtime.h>
#include <math.h>

#define NR 5
#define NB 7
#define NS 119
#define NA 25000
#define NE 1000000
#define OC 360           // output columns per atom
#define MUS 100          // unique moment floats per atom
#define CAPR 96          // record bin capacity (lambda=40, max ~68, overflow ~1e-15)
#define CAPI 112         // id bin capacity (fallback path)
#define CHUNK 64         // atoms per accum/contract block
#define MPAD 101         // LDS stride: gcd(101,32)=1 -> conflict-free

// tril index tables (wave-uniform index -> scalar loads)
static constexpr int T2I[15] = {0,1,1,2,2,2,3,3,3,3,4,4,4,4,4};
static constexpr int T2J[15] = {0,0,1,0,1,2,0,1,2,3,0,1,2,3,4};
static constexpr int T3I[35] = {0,1,1,1,2,2,2,2,2,2,3,3,3,3,3,3,3,3,3,3,4,4,4,4,4,4,4,4,4,4,4,4,4,4,4};
static constexpr int T3J[35] = {0,0,1,1,0,1,1,2,2,2,0,1,1,2,2,2,3,3,3,3,0,1,1,2,2,2,3,3,3,3,4,4,4,4,4};
static constexpr int T3K[35] = {0,0,0,1,0,0,1,0,1,2,0,0,1,0,1,2,0,1,2,3,0,0,1,0,1,2,0,1,2,3,0,1,2,3,4};

static constexpr int P2[9]  = {0,1,2, 1,3,4, 2,4,5};
static constexpr int P3[27] = {0,1,4, 1,2,5, 4,5,7,
                               1,2,5, 2,3,6, 5,6,8,
                               4,5,7, 5,6,8, 7,8,9};
static constexpr float W2[6]  = {1.f,2.f,2.f,1.f,2.f,1.f};
static constexpr float W3[10] = {1.f,3.f,3.f,1.f,3.f,6.f,3.f,3.f,3.f,1.f};

// moment m -> (rad index, product index). P[0]=1, P[1..3]=d, P[4..9]=q2, P[10..19]=q3
static constexpr int MR[100] = {
    0,1,2,3,4,
    0,0,0,1,1,1,2,2,2,3,3,3,4,4,4,
    0,0,0,0,0,0, 1,1,1,1,1,1, 2,2,2,2,2,2, 3,3,3,3,3,3, 4,4,4,4,4,4,
    0,0,0,0,0,0,0,0,0,0, 1,1,1,1,1,1,1,1,1,1, 2,2,2,2,2,2,2,2,2,2,
    3,3,3,3,3,3,3,3,3,3, 4,4,4,4,4,4,4,4,4,4};
static constexpr int MP[100] = {
    0,0,0,0,0,
    1,2,3,1,2,3,1,2,3,1,2,3,1,2,3,
    4,5,6,7,8,9, 4,5,6,7,8,9, 4,5,6,7,8,9, 4,5,6,7,8,9, 4,5,6,7,8,9,
    10,11,12,13,14,15,16,17,18,19, 10,11,12,13,14,15,16,17,18,19,
    10,11,12,13,14,15,16,17,18,19, 10,11,12,13,14,15,16,17,18,19,
    10,11,12,13,14,15,16,17,18,19};

template<int S>
__device__ __forceinline__ void accum25(float acc[25], const float rad[5], const float P[20])
{
#pragma unroll
    for (int i = 0; i < 25; i++)
        acc[i] += rad[MR[S*25 + i]] * P[MP[S*25 + i]];   // all indices compile-time
}

// ============================ FAST PATH ==================================
// Final config = R11 verbatim (measured best: 175.0us). Ledger:
// - pass 1 is a random-64B-line scatter floor (~14 G lines/s): invariant
//   across atomics/sort, counter padding, gather vectorization, alignment,
//   bin layout, byte count (8 structural variants, 67-95us).
// - pass 2: transposed bins -> coalesced reads; 4 slices x 4 subs, acc[25]
//   (no spill; acc[50] at the 128-VGPR/1024-thread cap regressed +16us).
// - R12's dr>=6 skip and R10's pair-read: traffic-positive but time-neutral
//   (inside the ±10us total noise band) -> dropped in favor of the exact
//   best-measured configuration.

// pass 1: fused edge compute + record scatter (transposed slot layout).
__global__ __launch_bounds__(256) void edge_record_kernel(
    const float* __restrict__ dr_vec, const int* __restrict__ Z,
    const int* __restrict__ nbr, const float* __restrict__ coeffs,
    int* __restrict__ cursor, float* __restrict__ binrec)
{
    int e = blockIdx.x * 256 + threadIdx.x;
    if (e >= NE) return;
    float x = dr_vec[3*e+0], y = dr_vec[3*e+1], z = dr_vec[3*e+2];
    int ai = nbr[e];
    int aj = nbr[NE + e];
    int Zi = Z[ai], Zj = Z[aj];

    float dr  = sqrtf(x*x + y*y + z*z);
    float inv = 1.0f / (dr + 1e-5f);
    float d0 = x*inv, d1 = y*inv, d2 = z*inv;

    const float PI_F = 3.14159265358979323846f;
    const float betta = 49.0f / 36.0f;
    const float rad_norm = 0.89812905f;          // (2*betta/pi)^0.75, folded
    float cut = (dr < 6.0f) ? 0.5f*(cosf(PI_F * dr * (1.0f/6.0f)) + 1.0f) : 0.0f;
    float scale = cut * 0.3779644730092272272f * rad_norm;   // cut/sqrt(7)*norm

    float basis[NB];
#pragma unroll
    for (int b = 0; b < NB; b++) {
        float t = dr - (float)b;
        basis[b] = expf(-betta * t * t);
    }

    const float* cp = coeffs + ((size_t)(Zi*NS + Zj)) * (NR*NB);
    float rad[NR];
#pragma unroll
    for (int r = 0; r < NR; r++) {
        float s = 0.f;
#pragma unroll
        for (int b = 0; b < NB; b++) s += basis[b] * cp[r*NB + b];
        rad[r] = s * scale;
    }

    int pos = __hip_atomic_fetch_add(&cursor[aj], 1, __ATOMIC_RELAXED, __HIP_MEMORY_SCOPE_AGENT);
    if (pos < CAPR) {
        // transposed: row = record index, col = atom -> accum reads coalesce
        float4* rp = (float4*)(binrec + ((size_t)pos * NA + aj) * 8);
        rp[0] = make_float4(rad[0], rad[1], rad[2], rad[3]);
        rp[1] = make_float4(rad[4], d0, d1, d2);
    }
}

// pass 2: accumulate + contract. 1024 threads = 16 waves:
// wave = (sub, slice): slice owns 25 moments (wave-uniform, constant regs),
// sub strides records by 4. Transposed bins: lane=atom, record p read at
// (p*NA + a)*32B -> 64 lanes cover one dense 2KB span (coalesced).
__global__ __launch_bounds__(1024) void accum_contract_kernel(
    const int* __restrict__ cursor, const float* __restrict__ binrec,
    float* __restrict__ out)
{
    __shared__ float lds[CHUNK * MPAD];
    int bl  = blockIdx.x * CHUNK;
    int nat = min(CHUNK, NA - bl);

    int wave  = threadIdx.x >> 6;     // 0..15
    int lane  = threadIdx.x & 63;     // local atom
    int slice = wave & 3;             // moment slice (25 moments)
    int sub   = wave >> 2;            // record subset (stride 4)

    int a = bl + lane;
    int n = (a < NA) ? min(cursor[a], CAPR) : 0;

    float acc[25];
#pragma unroll
    for (int i = 0; i < 25; i++) acc[i] = 0.f;

    const float* bp = binrec + (size_t)a * 8;   // column base for this atom
    for (int p = sub; p < n; p += 4) {
        const float4* rp = (const float4*)(bp + (size_t)p * NA * 8);
        float4 r0 = rp[0], r1 = rp[1];
        float rad[5] = {r0.x, r0.y, r0.z, r0.w, r1.x};
        float d0 = r1.y, d1 = r1.z, d2 = r1.w;

        float P[20];
        P[0] = 1.f; P[1] = d0; P[2] = d1; P[3] = d2;
        P[4] = d0*d0; P[5] = d1*d0; P[6] = d2*d0;
        P[7] = d1*d1; P[8] = d2*d1; P[9] = d2*d2;
        P[10] = d0*P[4]; P[11] = d1*P[4]; P[12] = d0*P[7]; P[13] = d1*P[7];
        P[14] = d2*P[4]; P[15] = d2*P[5]; P[16] = d2*P[7]; P[17] = d0*P[9];
        P[18] = d1*P[9]; P[19] = d2*P[9];

        switch (slice) {              // wave-uniform: no divergence
            case 0: accum25<0>(acc, rad, P); break;
            case 1: accum25<1>(acc, rad, P); break;
            case 2: accum25<2>(acc, rad, P); break;
            default: accum25<3>(acc, rad, P); break;
        }
    }

    // merge the 4 record-subsets: ordered rounds, slices disjoint per round
    float* dst = &lds[lane * MPAD + slice * 25];
    for (int s = 0; s < 4; s++) {
        if (sub == s) {
            if (s == 0) {
#pragma unroll
                for (int i = 0; i < 25; i++) dst[i] = acc[i];
            } else {
#pragma unroll
                for (int i = 0; i < 25; i++) dst[i] += acc[i];
            }
        }
        __syncthreads();
    }

    // ---- contract phase: lanes = atoms, 16 waves split the 360 columns ----
    int a2 = bl + lane;
    bool valid = (lane < nat);
    int mb = lane * MPAD;

#define ML(o) lds[mb + (o)]

    for (int cc = wave; cc < 360; cc += 16) {
        if (!valid) continue;
        float v; int dest;

        if (cc < 5) {
            v = ML(cc);
            dest = a2 * OC + cc;
        } else if (cc < 20) {
            int l = cc - 5;
            int r = T2I[l], s = T2J[l];
            float acc2 = 0.f;
#pragma unroll
            for (int i = 0; i < 3; i++) acc2 += ML(5 + r*3 + i) * ML(5 + s*3 + i);
            v = acc2;
            int f = l * NA + a2; int aa = f / 15; dest = aa * OC + 5 + (f - aa*15);
        } else if (cc < 35) {
            int l = cc - 20;
            int r = T2I[l], s = T2J[l];
            float acc2 = 0.f;
#pragma unroll
            for (int p2 = 0; p2 < 6; p2++) acc2 += W2[p2] * ML(20 + r*6 + p2) * ML(20 + s*6 + p2);
            v = acc2;
            int f = l * NA + a2; int aa = f / 15; dest = aa * OC + 20 + (f - aa*15);
        } else if (cc < 50) {
            int l = cc - 35;
            int r = T2I[l], s = T2J[l];
            float acc2 = 0.f;
#pragma unroll
            for (int p2 = 0; p2 < 10; p2++) acc2 += W3[p2] * ML(50 + r*10 + p2) * ML(50 + s*10 + p2);
            v = acc2;
            int f = l * NA + a2; int aa = f / 15; dest = aa * OC + 35 + (f - aa*15);
        } else if (cc < 85) {
            int l = cc - 50;
            int r = T3I[l], s = T3J[l], t = T3K[l];
            float R[6], S[6], T[6];
#pragma unroll
            for (int p2 = 0; p2 < 6; p2++) { R[p2]=ML(20+r*6+p2); S[p2]=ML(20+s*6+p2); T[p2]=ML(20+t*6+p2); }
            float acc2 = 0.f;
#pragma unroll
            for (int i = 0; i < 3; i++)
#pragma unroll
            for (int j = 0; j < 3; j++)
#pragma unroll
            for (int k = 0; k < 3; k++)
                acc2 += R[P2[i*3+j]] * S[P2[i*3+k]] * T[P2[j*3+k]];
            v = acc2;
            int f = l * NA + a2; int aa = f / 35; dest = aa * OC + 50 + (f - aa*35);
        } else if (cc < 160) {
            int l = cc - 85;
            int p2 = l / 5, t = l - p2*5;
            int r = T2I[p2], s = T2J[p2];
            float T[6];
#pragma unroll
            for (int q = 0; q < 6; q++) T[q] = ML(20 + t*6 + q);
            float acc2 = 0.f;
#pragma unroll
            for (int i = 0; i < 3; i++)
#pragma unroll
            for (int j = 0; j < 3; j++)
                acc2 += ML(5 + r*3 + i) * ML(5 + s*3 + j) * T[P2[i*3+j]];
            v = acc2;
            int f = l * NA + a2; int aa = f / 75; dest = aa * OC + 85 + (f - aa*75);
        } else if (cc < 235) {
            int l = cc - 160;
            int p2 = l / 5, t = l - p2*5;
            int r = T2I[p2], s = T2J[p2];
            float R[10], S[10], T[6];
#pragma unroll
            for (int q = 0; q < 10; q++) { R[q]=ML(50+r*10+q); S[q]=ML(50+s*10+q); }
#pragma unroll
            for (int q = 0; q < 6;  q++) T[q] = ML(20 + t*6 + q);
            float acc2 = 0.f;
#pragma unroll
            for (int k = 0; k < 3; k++)
#pragma unroll
            for (int l2 = 0; l2 < 3; l2++) {
                float inner = 0.f;
#pragma unroll
                for (int i = 0; i < 3; i++)
#pragma unroll
                for (int j = 0; j < 3; j++)
                    inner += R[P3[(i*3+j)*3+k]] * S[P3[(i*3+j)*3+l2]];
                acc2 += inner * T[P2[k*3+l2]];
            }
            v = acc2;
            int f = l * NA + a2; int aa = f / 75; dest = aa * OC + 160 + (f - aa*75);
        } else {
            int l = cc - 235;
            int r = l / 25; int rem = l - r*25; int s = rem / 5; int t = rem - s*5;
            float R[10], S[6], T1[3];
#pragma unroll
            for (int q = 0; q < 10; q++) R[q] = ML(50 + r*10 + q);
#pragma unroll
            for (int q = 0; q < 6;  q++) S[q] = ML(20 + s*6 + q);
#pragma unroll
            for (int q = 0; q < 3;  q++) T1[q] = ML(5 + t*3 + q);
            float acc2 = 0.f;
#pragma unroll
            for (int i = 0; i < 3; i++)
#pragma unroll
            for (int j = 0; j < 3; j++)
#pragma unroll
            for (int k = 0; k < 3; k++)
                acc2 += R[P3[(i*3+j)*3+k]] * S[P2[i*3+j]] * T1[k];
            v = acc2;
            int f = l * NA + a2; int aa = f / 125; dest = aa * OC + 235 + (f - aa*125);
        }
        out[dest] = v;
    }
#undef ML
}

// ========================= FALLBACK PATH =======================
__global__ __launch_bounds__(256) void scatter_kernel(
    const int* __restrict__ nbr, int* __restrict__ cursor, int* __restrict__ bins)
{
    int e = blockIdx.x * 256 + threadIdx.x;
    if (e >= NE) return;
    int aj = nbr[NE + e];
    int pos = __hip_atomic_fetch_add(&cursor[aj], 1, __ATOMIC_RELAXED, __HIP_MEMORY_SCOPE_AGENT);
    if (pos < CAPI) bins[(size_t)aj * CAPI + pos] = e;
}

__global__ __launch_bounds__(256) void accum_kernel(
    const float* __restrict__ dr_vec, const int* __restrict__ Z,
    const int* __restrict__ nbr, const float* __restrict__ coeffs,
    const int* __restrict__ cursor, const int* __restrict__ bins,
    float* __restrict__ Mu)
{
    __shared__ float red[32 * MUS];
    int t   = blockIdx.x * 256 + threadIdx.x;
    int a   = t >> 3;
    int sub = t & 7;
    int al  = threadIdx.x >> 3;
    int n   = (a < NA) ? min(cursor[a], CAPI) : 0;
    int Zj  = (a < NA) ? Z[a] : 0;

    float acc[MUS];
#pragma unroll
    for (int i = 0; i < MUS; i++) acc[i] = 0.f;

    const int* mybin = bins + (size_t)a * CAPI;
    const float PI_F = 3.14159265358979323846f;
    const float betta = 49.0f / 36.0f;
    float rad_norm = 0.89812905f;

    for (int p = sub; p < n; p += 8) {
        int e = mybin[p];
        float x = dr_vec[3*e+0], y = dr_vec[3*e+1], z = dr_vec[3*e+2];
        int Zi = Z[nbr[e]];

        float dr  = sqrtf(x*x + y*y + z*z);
        float inv = 1.0f / (dr + 1e-5f);
        float d0 = x*inv, d1 = y*inv, d2 = z*inv;

        float cut = (dr < 6.0f) ? 0.5f*(cosf(PI_F * dr * (1.0f/6.0f)) + 1.0f) : 0.0f;
        float scale = cut * 0.3779644730092272272f * rad_norm;

        float basis[NB];
#pragma unroll
        for (int b = 0; b < NB; b++) {
            float tt = dr - (float)b;
            basis[b] = expf(-betta * tt * tt);
        }

        const float* cp = coeffs + ((size_t)(Zi*NS + Zj)) * (NR*NB);
        float rad[NR];
#pragma unroll
        for (int r = 0; r < NR; r++) {
            float s = 0.f;
#pragma unroll
            for (int b = 0; b < NB; b++) s += basis[b] * cp[r*NB + b];
            rad[r] = s * scale;
        }

        float q2[6] = {d0*d0, d1*d0, d2*d0, d1*d1, d2*d1, d2*d2};
        float q3[10] = {d0*q2[0], d1*q2[0], d0*q2[3], d1*q2[3], d2*q2[0],
                        d2*q2[1], d2*q2[3], d0*q2[5], d1*q2[5], d2*q2[5]};

#pragma unroll
        for (int r = 0; r < NR; r++) {
            float rv = rad[r];
            acc[r] += rv;
            acc[5 + r*3 + 0] += rv*d0;
            acc[5 + r*3 + 1] += rv*d1;
            acc[5 + r*3 + 2] += rv*d2;
#pragma unroll
            for (int q = 0; q < 6; q++)  acc[20 + r*6  + q] += rv*q2[q];
#pragma unroll
            for (int q = 0; q < 10; q++) acc[50 + r*10 + q] += rv*q3[q];
        }
    }

#pragma unroll
    for (int i = 0; i < MUS; i++) {
        float v = acc[i];
        v += __shfl_xor(v, 1, 64);
        v += __shfl_xor(v, 2, 64);
        v += __shfl_xor(v, 4, 64);
        if (sub == 0) red[al * MUS + i] = v;
    }
    __syncthreads();

    for (int u = threadIdx.x; u < 32 * MUS; u += 256) {
        int ga = blockIdx.x * 32 + u / MUS;
        if (ga < NA) Mu[(size_t)ga * MUS + (u - (u / MUS) * MUS)] = red[u];
    }
}

__global__ __launch_bounds__(256) void contract_kernel(
    const float* __restrict__ Mu, float* __restrict__ out)
{
    __shared__ float lds[64 * MPAD];
    int base = blockIdx.x * 64;
    int nat  = min(64, NA - base);

    for (int t = threadIdx.x; t < nat * MUS; t += 256) {
        int al = t / MUS, off = t - al * MUS;
        lds[al * MPAD + off] = Mu[(size_t)base * MUS + t];
    }
    __syncthreads();

    int wave = threadIdx.x >> 6, lane = threadIdx.x & 63;
    int a2 = base + lane;
    bool valid = (lane < nat);
    int mb = lane * MPAD;

#define ML(o) lds[mb + (o)]

    for (int cc = wave; cc < 360; cc += 4) {
        if (!valid) continue;
        float v; int dest;

        if (cc < 5) {
            v = ML(cc);
            dest = a2 * OC + cc;
        } else if (cc < 20) {
            int l = cc - 5;
            int r = T2I[l], s = T2J[l];
            float acc = 0.f;
#pragma unroll
            for (int i = 0; i < 3; i++) acc += ML(5 + r*3 + i) * ML(5 + s*3 + i);
            v = acc;
            int f = l * NA + a2; int aa = f / 15; dest = aa * OC + 5 + (f - aa*15);
        } else if (cc < 35) {
            int l = cc - 20;
            int r = T2I[l], s = T2J[l];
            float acc = 0.f;
#pragma unroll
            for (int p = 0; p < 6; p++) acc += W2[p] * ML(20 + r*6 + p) * ML(20 + s*6 + p);
            v = acc;
            int f = l * NA + a2; int aa = f / 15; dest = aa * OC + 20 + (f - aa*15);
        } else if (cc < 50) {
            int l = cc - 35;
            int r = T2I[l], s = T2J[l];
            float acc = 0.f;
#pragma unroll
            for (int p = 0; p < 10; p++) acc += W3[p] * ML(50 + r*10 + p) * ML(50 + s*10 + p);
            v = acc;
            int f = l * NA + a2; int aa = f / 15; dest = aa * OC + 35 + (f - aa*15);
        } else if (cc < 85) {
            int l = cc - 50;
            int r = T3I[l], s = T3J[l], t = T3K[l];
            float R[6], S[6], T[6];
#pragma unroll
            for (int p = 0; p < 6; p++) { R[p]=ML(20+r*6+p); S[p]=ML(20+s*6+p); T[p]=ML(20+t*6+p); }
            float acc = 0.f;
#pragma unroll
            for (int i = 0; i < 3; i++)
#pragma unroll
            for (int j = 0; j < 3; j++)
#pragma unroll
            for (int k = 0; k < 3; k++)
                acc += R[P2[i*3+j]] * S[P2[i*3+k]] * T[P2[j*3+k]];
            v = acc;
            int f = l * NA + a2; int aa = f / 35; dest = aa * OC + 50 + (f - aa*35);
        } else if (cc < 160) {
            int l = cc - 85;
            int p = l / 5, t = l - p*5;
            int r = T2I[p], s = T2J[p];
            float T[6];
#pragma unroll
            for (int q = 0; q < 6; q++) T[q] = ML(20 + t*6 + q);
            float acc = 0.f;
#pragma unroll
            for (int i = 0; i < 3; i++)
#pragma unroll
            for (int j = 0; j < 3; j++)
                acc += ML(5 + r*3 + i) * ML(5 + s*3 + j) * T[P2[i*3+j]];
            v = acc;
            int f = l * NA + a2; int aa = f / 75; dest = aa * OC + 85 + (f - aa*75);
        } else if (cc < 235) {
            int l = cc - 160;
            int p = l / 5, t = l - p*5;
            int r = T2I[p], s = T2J[p];
            float R[10], S[10], T[6];
#pragma unroll
            for (int q = 0; q < 10; q++) { R[q]=ML(50+r*10+q); S[q]=ML(50+s*10+q); }
#pragma unroll
            for (int q = 0; q < 6;  q++) T[q] = ML(20 + t*6 + q);
            float acc = 0.f;
#pragma unroll
            for (int k = 0; k < 3; k++)
#pragma unroll
            for (int l2 = 0; l2 < 3; l2++) {
                float inner = 0.f;
#pragma unroll
                for (int i = 0; i < 3; i++)
#pragma unroll
                for (int j = 0; j < 3; j++)
                    inner += R[P3[(i*3+j)*3+k]] * S[P3[(i*3+j)*3+l2]];
                acc += inner * T[P2[k*3+l2]];
            }
            v = acc;
            int f = l * NA + a2; int aa = f / 75; dest = aa * OC + 160 + (f - aa*75);
        } else {
            int l = cc - 235;
            int r = l / 25; int rem = l - r*25; int s = rem / 5; int t = rem - s*5;
            float R[10], S[6], T1[3];
#pragma unroll
            for (int q = 0; q < 10; q++) R[q] = ML(50 + r*10 + q);
#pragma unroll
            for (int q = 0; q < 6;  q++) S[q] = ML(20 + s*6 + q);
#pragma unroll
            for (int q = 0; q < 3;  q++) T1[q] = ML(5 + t*3 + q);
            float acc = 0.f;
#pragma unroll
            for (int i = 0; i < 3; i++)
#pragma unroll
            for (int j = 0; j < 3; j++)
#pragma unroll
            for (int k = 0; k < 3; k++)
                acc += R[P3[(i*3+j)*3+k]] * S[P2[i*3+j]] * T1[k];
            v = acc;
            int f = l * NA + a2; int aa = f / 125; dest = aa * OC + 235 + (f - aa*125);
        }
        out[dest] = v;
    }
#undef ML
}

extern "C" void kernel_launch(void* const* d_in, const int* in_sizes, int n_in,
                              void* d_out, int out_size, void* d_ws, size_t ws_size,
                              hipStream_t stream) {
    const float* dr_vec = (const float*)d_in[0];
    const int*   Z      = (const int*)d_in[1];
    const int*   nbr    = (const int*)d_in[2];
    const float* coeffs = (const float*)d_in[3];
    float* out = (float*)d_out;

    // fast path: binrec FIRST (76.8MB, 64B-aligned), then cursor[NA]
    size_t binrec_fl = (size_t)NA * CAPR * 8;          // floats
    size_t need_fast = binrec_fl * sizeof(float) + (size_t)NA * sizeof(int);

    if (ws_size >= need_fast) {
        float* binrec = (float*)d_ws;
        int*   cursor = (int*)(binrec + binrec_fl);
        hipMemsetAsync(cursor, 0, (size_t)NA * sizeof(int), stream);
        edge_record_kernel<<<(NE + 255)/256, 256, 0, stream>>>(dr_vec, Z, nbr, coeffs, cursor, binrec);
        accum_contract_kernel<<<(NA + CHUNK - 1)/CHUNK, 1024, 0, stream>>>(cursor, binrec, out);
    } else {
        // fallback: cursor[NA] | bins[NA*CAPI] | Mu[NA*MUS] (~21.3 MB)
        int*   cursor = (int*)d_ws;
        int*   bins   = cursor + NA;
        float* Mu     = (float*)(bins + (size_t)NA * CAPI);
        hipMemsetAsync(cursor, 0, (size_t)NA * sizeof(int), stream);
        scatter_kernel<<<(NE + 255)/256, 256, 0, stream>>>(nbr, cursor, bins);
        accum_kernel<<<(NA*8 + 255)/256, 256, 0, stream>>>(dr_vec, Z, nbr, coeffs, cursor, bins, Mu);
        contract_kernel<<<(NA + 63)/64, 256, 0, stream>>>(Mu, out);
    }
}